// Round 3
// baseline (360.888 us; speedup 1.0000x reference)
//
#include <hip/hip_runtime.h>
#include <math.h>

typedef __attribute__((ext_vector_type(8))) short short8;
typedef __attribute__((ext_vector_type(16))) float f32x16;

#define D      128
#define NSEG   64
#define SEGC   1600          // candidates per segment (multiple of 64)
#define NTILES 25            // SEGC / 64
#define KTOP   10
#define CAP    128
#define DELTA  3.0f
// padded candidate rows: NSEG*SEGC + 64 (for last-tile prefetch overrun)
#define NPAD   (NSEG * SEGC + 64)
#define ROWU   144           // ushorts per padded candidate row (288 B): 128 data + x2w hi/lo + zeros

// ---------- helpers ----------
__device__ __forceinline__ ushort f2bf(float f) {
    uint u = __float_as_uint(f);
    uint r = (u + 0x7FFFu + ((u >> 16) & 1u)) >> 16;
    return (ushort)r;
}

__device__ __forceinline__ uint packx2(float x2w) {
    ushort h = f2bf(x2w);
    float hf = __uint_as_float(((uint)h) << 16);
    ushort lo = f2bf(x2w - hf);
    return (uint)h | ((uint)lo << 16);
}

__device__ __forceinline__ void insert10(float s, float v, float ls[KTOP], float lw[KTOP]) {
    ls[9] = s; lw[9] = v;
#pragma unroll
    for (int p = 9; p > 0; --p) {
        bool sw = ls[p] < ls[p - 1];
        float ts = sw ? ls[p - 1] : ls[p];
        float tl = sw ? ls[p]     : ls[p - 1];
        float tv = sw ? lw[p - 1] : lw[p];
        float tu = sw ? lw[p]     : lw[p - 1];
        ls[p] = ts; ls[p - 1] = tl;
        lw[p] = tv; lw[p - 1] = tu;
    }
}

// ---------- fused prep: candidates (padded rows, bf16 + x2w hi/lo), queries, cnt zero ----------
// one wave per row; candidate blocks first, then query blocks.
__global__ void prep_kernel(const float* __restrict__ Xt, const float* __restrict__ X,
                            const float* __restrict__ w,
                            ushort* __restrict__ Xbp, ushort* __restrict__ Xtb,
                            float* __restrict__ x2wf, float* __restrict__ q2f,
                            int* __restrict__ cnt, int n, int m, int nblocksA) {
    int wave = threadIdx.x >> 6, lane = threadIdx.x & 63;
    if ((int)blockIdx.x < nblocksA) {
        int row = blockIdx.x * 4 + wave;
        if (row >= NPAD) return;
        ushort* rowp = Xbp + (size_t)row * ROWU;
        if (row < n) {
            float2 v = ((const float2*)X)[(size_t)row * 64 + lane];
            ((ushort2*)rowp)[lane] = make_ushort2(f2bf(v.x), f2bf(v.y));
            float s = v.x * v.x + v.y * v.y;
#pragma unroll
            for (int o = 32; o; o >>= 1) s += __shfl_xor(s, o, 64);
            float x2w = s - w[row];                 // all lanes have it
            if (lane == 0) x2wf[row] = x2w;
            if (lane < 8) ((uint*)rowp)[64 + lane] = (lane == 0) ? packx2(x2w) : 0u;
        } else {
            ((ushort2*)rowp)[lane] = make_ushort2(0, 0);   // sentinel: zero data
            if (lane < 8) ((uint*)rowp)[64 + lane] = (lane == 0) ? packx2(1e30f) : 0u;
        }
    } else {
        int qb = blockIdx.x - nblocksA;
        int row = qb * 4 + wave;
        int tid = qb * 256 + threadIdx.x;
        if (tid < m) cnt[tid] = 0;
        if (row >= m) return;
        float2 v = ((const float2*)Xt)[(size_t)row * 64 + lane];
        ((ushort2*)Xtb)[(size_t)row * 64 + lane] = make_ushort2(f2bf(v.x), f2bf(v.y));
        float s = v.x * v.x + v.y * v.y;
#pragma unroll
        for (int o = 32; o; o >>= 1) s += __shfl_xor(s, o, 64);
        if (lane == 0) q2f[row] = s;
    }
}

__device__ __forceinline__ void emit_cand(int q, int c, int* cnt, int* buf) {
    int pos = atomicAdd(&cnt[q], 1);
    if (pos < CAP) buf[q * CAP + pos] = c;
}

// ---------- main GEMM pass: LDS-free, barrier-light, software-pipelined ----------
// block = 256 thr (4 waves) = 256 queries x one candidate segment.
// wave: 64 cands x 64 queries, A-fragments streamed global->reg, B in regs.
// acc = q.x - 0.5*x2w  =>  s = -2*acc.
template<int PASS>
__global__ __launch_bounds__(256, 2) void nd_pass(
        const ushort* __restrict__ Xbp, const ushort* __restrict__ Xtb,
        const float* __restrict__ tau, float* __restrict__ minbuf,
        int* __restrict__ cnt, int* __restrict__ buf, int m) {
    const int t = threadIdx.x;
    const int l = t & 63, wv = t >> 6;
    const int seg = blockIdx.y;
    const int qbase = blockIdx.x * 256;
    const int q0 = qbase + wv * 64 + (l & 31);
    const int half = l >> 5;
    const int segStart = seg * SEGC;

    // preload B fragments (loop-invariant, 72 VGPRs)
    short8 Bf[9][2];
#pragma unroll
    for (int s = 0; s < 8; ++s)
#pragma unroll
        for (int qb = 0; qb < 2; ++qb)
            Bf[s][qb] = *(const short8*)(Xtb + (size_t)(q0 + qb * 32) * D + s * 16 + half * 8);
    {
        short8 z = (short8)(short)0;
        if (l < 32) { z[0] = (short)0xBF00; z[1] = (short)0xBF00; }  // -0.5 at k=128,129
        Bf[8][0] = z; Bf[8][1] = z;
    }

    float tp0 = 0.f, tp1 = 0.f;
    if (PASS == 2) { tp0 = -0.5f * tau[q0]; tp1 = -0.5f * tau[q0 + 32]; }
    float mx0 = -INFINITY, mx1 = -INFINITY;

    // per-lane A pointers (short8 = 16B units, row = 18 units)
    const short8* pa0 = (const short8*)Xbp + (size_t)(segStart + (l & 31)) * 18 + half;
    const short8* pa1 = pa0 + 576;   // +32 rows

    short8 a0c = pa0[0], a1c = pa1[0];

    for (int tile = 0; tile < NTILES; ++tile) {
        f32x16 acc00 = (f32x16)0.f, acc01 = (f32x16)0.f;
        f32x16 acc10 = (f32x16)0.f, acc11 = (f32x16)0.f;
#pragma unroll
        for (int ks = 0; ks < 9; ++ks) {
            const int nx = (ks < 8) ? (ks + 1) * 2 : 1152;   // next kstep, or next tile ks0
            short8 a0n = pa0[nx], a1n = pa1[nx];
            acc00 = __builtin_amdgcn_mfma_f32_32x32x16_bf16(a0c, Bf[ks][0], acc00, 0, 0, 0);
            acc01 = __builtin_amdgcn_mfma_f32_32x32x16_bf16(a0c, Bf[ks][1], acc01, 0, 0, 0);
            acc10 = __builtin_amdgcn_mfma_f32_32x32x16_bf16(a1c, Bf[ks][0], acc10, 0, 0, 0);
            acc11 = __builtin_amdgcn_mfma_f32_32x32x16_bf16(a1c, Bf[ks][1], acc11, 0, 0, 0);
            a0c = a0n; a1c = a1n;
        }
        pa0 += 1152; pa1 += 1152;

        if (PASS == 1) {
#pragma unroll
            for (int r = 0; r < 16; ++r) {
                mx0 = fmaxf(mx0, fmaxf(acc00[r], acc10[r]));
                mx1 = fmaxf(mx1, fmaxf(acc01[r], acc11[r]));
            }
        } else {
            const int base = segStart + tile * 64;
            float h00 = -INFINITY, h01 = -INFINITY, h10 = -INFINITY, h11 = -INFINITY;
#pragma unroll
            for (int r = 0; r < 16; ++r) {
                h00 = fmaxf(h00, acc00[r]); h01 = fmaxf(h01, acc01[r]);
                h10 = fmaxf(h10, acc10[r]); h11 = fmaxf(h11, acc11[r]);
            }
            if (__any(h00 >= tp0)) {
#pragma unroll
                for (int r = 0; r < 16; ++r)
                    if (acc00[r] >= tp0) emit_cand(q0, base + (r & 3) + 8 * (r >> 2) + 4 * half, cnt, buf);
            }
            if (__any(h10 >= tp0)) {
#pragma unroll
                for (int r = 0; r < 16; ++r)
                    if (acc10[r] >= tp0) emit_cand(q0, base + 32 + (r & 3) + 8 * (r >> 2) + 4 * half, cnt, buf);
            }
            if (__any(h01 >= tp1)) {
#pragma unroll
                for (int r = 0; r < 16; ++r)
                    if (acc01[r] >= tp1) emit_cand(q0 + 32, base + (r & 3) + 8 * (r >> 2) + 4 * half, cnt, buf);
            }
            if (__any(h11 >= tp1)) {
#pragma unroll
                for (int r = 0; r < 16; ++r)
                    if (acc11[r] >= tp1) emit_cand(q0 + 32, base + 32 + (r & 3) + 8 * (r >> 2) + 4 * half, cnt, buf);
            }
        }
        __builtin_amdgcn_s_barrier();   // raw rendezvous (no LDS deps) -> keep waves L1-aligned
    }

    if (PASS == 1) {
        size_t rowi = (size_t)(seg * 2 + half) * m;
        minbuf[rowi + q0]      = -2.f * mx0;
        minbuf[rowi + q0 + 32] = -2.f * mx1;
    }
}

// ---------- tau: 10th smallest of 2*NSEG stream-mins per query, + margin ----------
__global__ void tau_kernel(const float* __restrict__ minbuf, float* __restrict__ tau, int m) {
    int q = blockIdx.x * blockDim.x + threadIdx.x;
    if (q >= m) return;
    float ms[KTOP];
#pragma unroll
    for (int e = 0; e < KTOP; ++e) ms[e] = INFINITY;
    for (int i = 0; i < 2 * NSEG; ++i) {
        float v = minbuf[(size_t)i * m + q];
        if (v < ms[9]) {
            ms[9] = v;
#pragma unroll
            for (int p = 9; p > 0; --p) {
                float a = fminf(ms[p - 1], ms[p]);
                float b = fmaxf(ms[p - 1], ms[p]);
                ms[p - 1] = a; ms[p] = b;
            }
        }
    }
    tau[q] = ms[9] + DELTA;
}

// ---------- exact fp32 rescore: wave per query, lane per candidate ----------
__global__ void rescore_kernel(const float* __restrict__ Xtf, const float* __restrict__ Xf,
                               const float* __restrict__ w, const float* __restrict__ x2wf,
                               const float* __restrict__ q2f, const int* __restrict__ cnt,
                               const int* __restrict__ buf, float* __restrict__ out, int m) {
    __shared__ float sS[CAP], sW[CAP];
    const int q = blockIdx.x, l = threadIdx.x;
    const int c = min(cnt[q], CAP);
    const bool v0 = l < c, v1 = l + 64 < c;
    const int j0 = v0 ? buf[q * CAP + l] : 0;
    const int j1 = v1 ? buf[q * CAP + l + 64] : 0;
    const float4* Q4 = (const float4*)Xtf + (size_t)q * 32;
    const float4* A4 = (const float4*)Xf + (size_t)j0 * 32;
    const float4* B4 = (const float4*)Xf + (size_t)j1 * 32;
    float acc0 = 0.f, acc1 = 0.f;
#pragma unroll 8
    for (int d = 0; d < 32; ++d) {
        float4 qv = Q4[d];
        float4 a = A4[d], b = B4[d];
        acc0 = fmaf(qv.x, a.x, fmaf(qv.y, a.y, fmaf(qv.z, a.z, fmaf(qv.w, a.w, acc0))));
        acc1 = fmaf(qv.x, b.x, fmaf(qv.y, b.y, fmaf(qv.z, b.z, fmaf(qv.w, b.w, acc1))));
    }
    sS[l]      = v0 ? (x2wf[j0] - 2.f * acc0) : INFINITY;
    sW[l]      = v0 ? w[j0] : 0.f;
    sS[l + 64] = v1 ? (x2wf[j1] - 2.f * acc1) : INFINITY;
    sW[l + 64] = v1 ? w[j1] : 0.f;
    __syncthreads();
    if (l == 0) {
        float ls[KTOP], lw[KTOP];
#pragma unroll
        for (int e = 0; e < KTOP; ++e) { ls[e] = INFINITY; lw[e] = 0.f; }
        for (int i = 0; i < c; ++i)
            if (sS[i] < ls[9]) insert10(sS[i], sW[i], ls, lw);
        float q2v = q2f[q];
        float mx = -INFINITY;
#pragma unroll
        for (int e = 0; e < KTOP; ++e) {
            if (ls[e] < 1e30f) {
                float d2 = fmaxf(q2v + ls[e] + lw[e], 0.f);
                mx = fmaxf(mx, lw[e] - sqrtf(d2));
            }
        }
        out[q] = mx;
    }
}

// ---------- launch ----------
extern "C" void kernel_launch(void* const* d_in, const int* in_sizes, int n_in,
                              void* d_out, int out_size, void* d_ws, size_t ws_size,
                              hipStream_t stream) {
    const float* Xt = (const float*)d_in[0];
    const float* X  = (const float*)d_in[1];
    const float* w  = (const float*)d_in[2];
    const int m = in_sizes[0] / D;   // 2048
    const int n = in_sizes[1] / D;   // 100000

    auto align256 = [](size_t x) { return (x + 255) & ~(size_t)255; };
    char* p = (char*)d_ws;
    ushort* Xbp  = (ushort*)p;  p += align256((size_t)NPAD * ROWU * 2);     // ~29.5 MB
    ushort* Xtb  = (ushort*)p;  p += align256((size_t)m * D * 2);
    float*  x2wf = (float*)p;   p += align256((size_t)n * 4);
    float*  q2f  = (float*)p;   p += align256((size_t)m * 4);
    float*  minb = (float*)p;   p += align256((size_t)2 * NSEG * m * 4);
    float*  tau  = (float*)p;   p += align256((size_t)m * 4);
    int*    cnt  = (int*)p;     p += align256((size_t)m * 4);
    int*    buf  = (int*)p;     p += align256((size_t)m * CAP * 4);

    const int nblocksA = (NPAD + 3) / 4;
    const int nblocksB = (m + 3) / 4;
    prep_kernel<<<nblocksA + nblocksB, 256, 0, stream>>>(Xt, X, w, Xbp, Xtb, x2wf, q2f, cnt, n, m, nblocksA);

    dim3 grid(m / 256, NSEG);
    nd_pass<1><<<grid, 256, 0, stream>>>(Xbp, Xtb, tau, minb, cnt, buf, m);
    tau_kernel<<<(m + 255) / 256, 256, 0, stream>>>(minb, tau, m);
    nd_pass<2><<<grid, 256, 0, stream>>>(Xbp, Xtb, tau, minb, cnt, buf, m);
    rescore_kernel<<<m, 64, 0, stream>>>(Xt, X, w, x2wf, q2f, cnt, buf, (float*)d_out, m);
}

// Round 4
// 327.654 us; speedup vs baseline: 1.1014x; 1.1014x over previous
//
#include <hip/hip_runtime.h>
#include <math.h>

typedef __attribute__((ext_vector_type(8))) short short8;
typedef __attribute__((ext_vector_type(16))) float f32x16;

#define D      128
#define NSEG   128
#define SEGC   800           // candidates per segment (multiple of 32)
#define NT     25            // SEGC / 32
#define TILE_C 32
#define KTOP   10
#define CAP    128
#define DELTA  3.0f
#define NPAD   (NSEG * SEGC + TILE_C)   // +32 rows for last prefetch overrun
#define ROWU   144           // ushorts per padded row (288 B): 128 data + x2w hi/lo + zeros
#define TUNITS (TILE_C * 18) // 576 16B-units per tile
#define BUFU   (TUNITS * 8)  // 4608 ushorts per LDS buffer

// ---------- helpers ----------
__device__ __forceinline__ ushort f2bf(float f) {
    uint u = __float_as_uint(f);
    uint r = (u + 0x7FFFu + ((u >> 16) & 1u)) >> 16;
    return (ushort)r;
}

__device__ __forceinline__ uint packx2(float x2w) {
    ushort h = f2bf(x2w);
    float hf = __uint_as_float(((uint)h) << 16);
    ushort lo = f2bf(x2w - hf);
    return (uint)h | ((uint)lo << 16);
}

__device__ __forceinline__ void insert10(float s, float v, float ls[KTOP], float lw[KTOP]) {
    ls[9] = s; lw[9] = v;
#pragma unroll
    for (int p = 9; p > 0; --p) {
        bool sw = ls[p] < ls[p - 1];
        float ts = sw ? ls[p - 1] : ls[p];
        float tl = sw ? ls[p]     : ls[p - 1];
        float tv = sw ? lw[p - 1] : lw[p];
        float tu = sw ? lw[p]     : lw[p - 1];
        ls[p] = ts; ls[p - 1] = tl;
        lw[p] = tv; lw[p - 1] = tu;
    }
}

__device__ __forceinline__ void gl_lds16(const ushort* g, ushort* l) {
    __builtin_amdgcn_global_load_lds((const __attribute__((address_space(1))) void*)g,
                                     (__attribute__((address_space(3))) void*)l, 16, 0, 0);
}

// ---------- fused prep: candidates (padded 288B rows, bf16 + x2w hi/lo), queries, cnt zero ----------
__global__ void prep_kernel(const float* __restrict__ Xt, const float* __restrict__ X,
                            const float* __restrict__ w,
                            ushort* __restrict__ Xbp, ushort* __restrict__ Xtb,
                            float* __restrict__ x2wf, float* __restrict__ q2f,
                            int* __restrict__ cnt, int n, int m, int nblocksA) {
    int wave = threadIdx.x >> 6, lane = threadIdx.x & 63;
    if ((int)blockIdx.x < nblocksA) {
        int row = blockIdx.x * 4 + wave;
        if (row >= NPAD) return;
        ushort* rowp = Xbp + (size_t)row * ROWU;
        if (row < n) {
            float2 v = ((const float2*)X)[(size_t)row * 64 + lane];
            ((ushort2*)rowp)[lane] = make_ushort2(f2bf(v.x), f2bf(v.y));
            float s = v.x * v.x + v.y * v.y;
#pragma unroll
            for (int o = 32; o; o >>= 1) s += __shfl_xor(s, o, 64);
            float x2w = s - w[row];
            if (lane == 0) x2wf[row] = x2w;
            if (lane < 8) ((uint*)rowp)[64 + lane] = (lane == 0) ? packx2(x2w) : 0u;
        } else {
            ((ushort2*)rowp)[lane] = make_ushort2(0, 0);      // sentinel: zero data
            if (lane < 8) ((uint*)rowp)[64 + lane] = (lane == 0) ? packx2(1e30f) : 0u;
        }
    } else {
        int qb = blockIdx.x - nblocksA;
        int row = qb * 4 + wave;
        int tid = qb * 256 + threadIdx.x;
        if (tid < m) cnt[tid] = 0;
        if (row >= m) return;
        float2 v = ((const float2*)Xt)[(size_t)row * 64 + lane];
        ((ushort2*)Xtb)[(size_t)row * 64 + lane] = make_ushort2(f2bf(v.x), f2bf(v.y));
        float s = v.x * v.x + v.y * v.y;
#pragma unroll
        for (int o = 32; o; o >>= 1) s += __shfl_xor(s, o, 64);
        if (lane == 0) q2f[row] = s;
    }
}

__device__ __forceinline__ void emit_cand(int q, int c, int* cnt, int* buf) {
    int pos = atomicAdd(&cnt[q], 1);
    if (pos < CAP) buf[q * CAP + pos] = c;
}

// ---------- main GEMM pass ----------
// 512 blocks = 128 segs x 4 query-blocks = 2 blocks/CU. Block: 4 waves x 128 queries each.
// Wave tile: 32 cands x 128 queries per k-step (4 MFMAs), B in regs, A via global_load_lds
// double-buffer. acc = q.x - 0.5*x2w  =>  s = -2*acc.
template<int PASS>
__global__ __launch_bounds__(256, 2) void nd_pass(
        const ushort* __restrict__ Xbp, const ushort* __restrict__ Xtb,
        const float* __restrict__ tau, float* __restrict__ minbuf,
        int* __restrict__ cnt, int* __restrict__ buf, int m) {
    __shared__ __align__(16) ushort As[2 * BUFU];   // 2 x 9216 B

    const int t = threadIdx.x;
    const int l = t & 63, wv = t >> 6;
    const int half = l >> 5;
    const int seg = blockIdx.x;
    const int qbase = blockIdx.y * 512 + wv * 128;
    const int q0 = qbase + (l & 31);                 // query for qsub 0 (qsub s -> +32*s)
    const int tile0 = seg * NT;

    // preload B fragments: [kstep][qsub]
    short8 Bf[9][4];
#pragma unroll
    for (int s = 0; s < 8; ++s)
#pragma unroll
        for (int qs = 0; qs < 4; ++qs)
            Bf[s][qs] = *(const short8*)(Xtb + (size_t)(q0 + qs * 32) * D + s * 16 + half * 8);
    {
        short8 z = (short8)(short)0;
        if (l < 32) { z[0] = (short)0xBF00; z[1] = (short)0xBF00; }  // -0.5 at k=128,129
#pragma unroll
        for (int qs = 0; qs < 4; ++qs) Bf[8][qs] = z;
    }

    float tp[4];
    float mx[4];
#pragma unroll
    for (int qs = 0; qs < 4; ++qs) {
        tp[qs] = (PASS == 2) ? (-0.5f * tau[q0 + qs * 32]) : 0.f;
        mx[qs] = -INFINITY;
    }

    // stage tile0 into buffer 0: wave wv stages units [wv*144, wv*144+144)
    {
        const ushort* g = Xbp + ((size_t)tile0 * TUNITS + wv * 144) * 8;
        ushort* ld = &As[(wv * 144) * 8];
        gl_lds16(g + (size_t)l * 8,        ld);
        gl_lds16(g + (size_t)(64 + l) * 8, ld + 64 * 8);
        if (l < 16) gl_lds16(g + (size_t)(128 + l) * 8, ld + 128 * 8);
    }

    for (int t2 = 0; t2 < NT; ++t2) {
        __syncthreads();   // drains staging of tile t2 (issued one full tile of compute ago)
        {   // prefetch tile t2+1 into the other buffer (pad rows exist for the overrun)
            const ushort* g = Xbp + ((size_t)(tile0 + t2 + 1) * TUNITS + wv * 144) * 8;
            ushort* ld = &As[((t2 + 1) & 1) * BUFU + (wv * 144) * 8];
            gl_lds16(g + (size_t)l * 8,        ld);
            gl_lds16(g + (size_t)(64 + l) * 8, ld + 64 * 8);
            if (l < 16) gl_lds16(g + (size_t)(128 + l) * 8, ld + 128 * 8);
        }

        const ushort* Ab = &As[(t2 & 1) * BUFU];
        f32x16 acc0 = (f32x16)0.f, acc1 = (f32x16)0.f, acc2 = (f32x16)0.f, acc3 = (f32x16)0.f;
#pragma unroll
        for (int ks = 0; ks < 9; ++ks) {
            const int kb = (ks < 8) ? (ks * 2 + half) : (16 + half);
            short8 a = *(const short8*)&Ab[((l & 31) * 18 + kb) * 8];
            acc0 = __builtin_amdgcn_mfma_f32_32x32x16_bf16(a, Bf[ks][0], acc0, 0, 0, 0);
            acc1 = __builtin_amdgcn_mfma_f32_32x32x16_bf16(a, Bf[ks][1], acc1, 0, 0, 0);
            acc2 = __builtin_amdgcn_mfma_f32_32x32x16_bf16(a, Bf[ks][2], acc2, 0, 0, 0);
            acc3 = __builtin_amdgcn_mfma_f32_32x32x16_bf16(a, Bf[ks][3], acc3, 0, 0, 0);
        }

        // epilogue: per-qsub max of acc (s = -2*acc, so max acc == min s)
        float h[4];
#pragma unroll
        for (int qs = 0; qs < 4; ++qs) h[qs] = -INFINITY;
#pragma unroll
        for (int r = 0; r < 16; ++r) {
            h[0] = fmaxf(h[0], acc0[r]); h[1] = fmaxf(h[1], acc1[r]);
            h[2] = fmaxf(h[2], acc2[r]); h[3] = fmaxf(h[3], acc3[r]);
        }
        if (PASS == 1) {
#pragma unroll
            for (int qs = 0; qs < 4; ++qs) mx[qs] = fmaxf(mx[qs], h[qs]);
        } else {
            const int base = (tile0 + t2) * TILE_C;
            if (__any(h[0] >= tp[0])) {
#pragma unroll
                for (int r = 0; r < 16; ++r)
                    if (acc0[r] >= tp[0]) emit_cand(q0,      base + (r & 3) + 8 * (r >> 2) + 4 * half, cnt, buf);
            }
            if (__any(h[1] >= tp[1])) {
#pragma unroll
                for (int r = 0; r < 16; ++r)
                    if (acc1[r] >= tp[1]) emit_cand(q0 + 32, base + (r & 3) + 8 * (r >> 2) + 4 * half, cnt, buf);
            }
            if (__any(h[2] >= tp[2])) {
#pragma unroll
                for (int r = 0; r < 16; ++r)
                    if (acc2[r] >= tp[2]) emit_cand(q0 + 64, base + (r & 3) + 8 * (r >> 2) + 4 * half, cnt, buf);
            }
            if (__any(h[3] >= tp[3])) {
#pragma unroll
                for (int r = 0; r < 16; ++r)
                    if (acc3[r] >= tp[3]) emit_cand(q0 + 96, base + (r & 3) + 8 * (r >> 2) + 4 * half, cnt, buf);
            }
        }
    }

    if (PASS == 1) {
        size_t rowi = (size_t)(seg * 2 + half) * m;
#pragma unroll
        for (int qs = 0; qs < 4; ++qs)
            minbuf[rowi + q0 + qs * 32] = -2.f * mx[qs];
    }
}

// ---------- tau: 10th smallest of 2*NSEG stream-mins per query, + margin ----------
__global__ void tau_kernel(const float* __restrict__ minbuf, float* __restrict__ tau, int m) {
    int q = blockIdx.x * blockDim.x + threadIdx.x;
    if (q >= m) return;
    float ms[KTOP];
#pragma unroll
    for (int e = 0; e < KTOP; ++e) ms[e] = INFINITY;
    for (int i = 0; i < 2 * NSEG; ++i) {
        float v = minbuf[(size_t)i * m + q];
        if (v < ms[9]) {
            ms[9] = v;
#pragma unroll
            for (int p = 9; p > 0; --p) {
                float a = fminf(ms[p - 1], ms[p]);
                float b = fmaxf(ms[p - 1], ms[p]);
                ms[p - 1] = a; ms[p] = b;
            }
        }
    }
    tau[q] = ms[9] + DELTA;
}

// ---------- exact fp32 rescore ----------
__global__ void rescore_kernel(const float* __restrict__ Xtf, const float* __restrict__ Xf,
                               const float* __restrict__ w, const float* __restrict__ x2wf,
                               const float* __restrict__ q2f, const int* __restrict__ cnt,
                               const int* __restrict__ buf, float* __restrict__ out, int m) {
    __shared__ float sS[CAP], sW[CAP];
    const int q = blockIdx.x, l = threadIdx.x;
    const int c = min(cnt[q], CAP);
    const bool v0 = l < c, v1 = l + 64 < c;
    const int j0 = v0 ? buf[q * CAP + l] : 0;
    const int j1 = v1 ? buf[q * CAP + l + 64] : 0;
    const float4* Q4 = (const float4*)Xtf + (size_t)q * 32;
    const float4* A4 = (const float4*)Xf + (size_t)j0 * 32;
    const float4* B4 = (const float4*)Xf + (size_t)j1 * 32;
    float acc0 = 0.f, acc1 = 0.f;
#pragma unroll 8
    for (int d = 0; d < 32; ++d) {
        float4 qv = Q4[d];
        float4 a = A4[d], b = B4[d];
        acc0 = fmaf(qv.x, a.x, fmaf(qv.y, a.y, fmaf(qv.z, a.z, fmaf(qv.w, a.w, acc0))));
        acc1 = fmaf(qv.x, b.x, fmaf(qv.y, b.y, fmaf(qv.z, b.z, fmaf(qv.w, b.w, acc1))));
    }
    sS[l]      = v0 ? (x2wf[j0] - 2.f * acc0) : INFINITY;
    sW[l]      = v0 ? w[j0] : 0.f;
    sS[l + 64] = v1 ? (x2wf[j1] - 2.f * acc1) : INFINITY;
    sW[l + 64] = v1 ? w[j1] : 0.f;
    __syncthreads();
    if (l == 0) {
        float ls[KTOP], lw[KTOP];
#pragma unroll
        for (int e = 0; e < KTOP; ++e) { ls[e] = INFINITY; lw[e] = 0.f; }
        for (int i = 0; i < c; ++i)
            if (sS[i] < ls[9]) insert10(sS[i], sW[i], ls, lw);
        float q2v = q2f[q];
        float mxv = -INFINITY;
#pragma unroll
        for (int e = 0; e < KTOP; ++e) {
            if (ls[e] < 1e30f) {
                float d2 = fmaxf(q2v + ls[e] + lw[e], 0.f);
                mxv = fmaxf(mxv, lw[e] - sqrtf(d2));
            }
        }
        out[q] = mxv;
    }
}

// ---------- launch ----------
extern "C" void kernel_launch(void* const* d_in, const int* in_sizes, int n_in,
                              void* d_out, int out_size, void* d_ws, size_t ws_size,
                              hipStream_t stream) {
    const float* Xt = (const float*)d_in[0];
    const float* X  = (const float*)d_in[1];
    const float* w  = (const float*)d_in[2];
    const int m = in_sizes[0] / D;   // 2048
    const int n = in_sizes[1] / D;   // 100000

    auto align256 = [](size_t x) { return (x + 255) & ~(size_t)255; };
    char* p = (char*)d_ws;
    ushort* Xbp  = (ushort*)p;  p += align256((size_t)NPAD * ROWU * 2);     // ~29.5 MB
    ushort* Xtb  = (ushort*)p;  p += align256((size_t)m * D * 2);
    float*  x2wf = (float*)p;   p += align256((size_t)n * 4);
    float*  q2f  = (float*)p;   p += align256((size_t)m * 4);
    float*  minb = (float*)p;   p += align256((size_t)2 * NSEG * m * 4);    // 2 MB
    float*  tau  = (float*)p;   p += align256((size_t)m * 4);
    int*    cnt  = (int*)p;     p += align256((size_t)m * 4);
    int*    buf  = (int*)p;     p += align256((size_t)m * CAP * 4);

    const int nblocksA = (NPAD + 3) / 4;
    const int nblocksB = (m + 3) / 4;
    prep_kernel<<<nblocksA + nblocksB, 256, 0, stream>>>(Xt, X, w, Xbp, Xtb, x2wf, q2f, cnt, n, m, nblocksA);

    dim3 grid(NSEG, m / 512);
    nd_pass<1><<<grid, 256, 0, stream>>>(Xbp, Xtb, tau, minb, cnt, buf, m);
    tau_kernel<<<(m + 255) / 256, 256, 0, stream>>>(minb, tau, m);
    nd_pass<2><<<grid, 256, 0, stream>>>(Xbp, Xtb, tau, minb, cnt, buf, m);
    rescore_kernel<<<m, 64, 0, stream>>>(Xt, X, w, x2wf, q2f, cnt, buf, (float*)d_out, m);
}

// Round 7
// 269.835 us; speedup vs baseline: 1.3374x; 1.2143x over previous
//
#include <hip/hip_runtime.h>
#include <math.h>

typedef __attribute__((ext_vector_type(8))) short short8;
typedef __attribute__((ext_vector_type(16))) float f32x16;

#define D      128
#define NSEG   128
#define SEGC   800           // candidates per segment (multiple of 32)
#define NT     25            // SEGC / 32
#define TILE_C 32
#define KTOP   10
#define CAP    128
#define DELTA  3.0f
#define NPAD   (NSEG * SEGC + TILE_C)   // +32 rows for last-tile prefetch overrun (== 102432)
#define ROWU   144           // ushorts per padded row (288 B): 128 data + x2w hi/lo + zeros
#define TUNITS (TILE_C * 18) // 576 16B-units per tile
#define BUFU   (TUNITS * 8)  // 4608 ushorts per LDS buffer

// LDS swizzle: unit (r,kb) stored at r*18 + (kb ^ ((r>>2)&1)).  Flipping kb-bit0 by row-bit2
// makes each consecutive-8-lane b128 phase hit 8 distinct bank-quads (conflict-free).
__device__ __forceinline__ int lds_unit(int u) {
    int r = u / 18, kb = u % 18;
    return r * 18 + (kb ^ ((r >> 2) & 1));
}

// ---------- helpers ----------
__device__ __forceinline__ ushort f2bf(float f) {
    uint u = __float_as_uint(f);
    uint r = (u + 0x7FFFu + ((u >> 16) & 1u)) >> 16;
    return (ushort)r;
}

__device__ __forceinline__ uint packx2(float x2w) {
    ushort h = f2bf(x2w);
    float hf = __uint_as_float(((uint)h) << 16);
    ushort lo = f2bf(x2w - hf);
    return (uint)h | ((uint)lo << 16);
}

__device__ __forceinline__ void insert10(float s, float v, float ls[KTOP], float lw[KTOP]) {
    ls[9] = s; lw[9] = v;
#pragma unroll
    for (int p = 9; p > 0; --p) {
        bool sw = ls[p] < ls[p - 1];
        float ts = sw ? ls[p - 1] : ls[p];
        float tl = sw ? ls[p]     : ls[p - 1];
        float tv = sw ? lw[p - 1] : lw[p];
        float tu = sw ? lw[p]     : lw[p - 1];
        ls[p] = ts; ls[p - 1] = tl;
        lw[p] = tv; lw[p - 1] = tu;
    }
}

__device__ __forceinline__ void insert10s(float s, float ms[KTOP]) {
    ms[9] = s;
#pragma unroll
    for (int p = 9; p > 0; --p) {
        float a = fminf(ms[p - 1], ms[p]);
        float b = fmaxf(ms[p - 1], ms[p]);
        ms[p - 1] = a; ms[p] = b;
    }
}

// ---------- fused prep: candidates (padded 288B rows, bf16 + x2w hi/lo), queries, cnt zero ----------
__global__ void prep_kernel(const float* __restrict__ Xt, const float* __restrict__ X,
                            const float* __restrict__ w,
                            ushort* __restrict__ Xbp, ushort* __restrict__ Xtb,
                            float* __restrict__ x2wf, float* __restrict__ q2f,
                            int* __restrict__ cnt, int n, int m, int nblocksA) {
    int wave = threadIdx.x >> 6, lane = threadIdx.x & 63;
    if ((int)blockIdx.x < nblocksA) {
        int row = blockIdx.x * 4 + wave;
        if (row >= NPAD) return;
        ushort* rowp = Xbp + (size_t)row * ROWU;
        if (row < n) {
            float2 v = ((const float2*)X)[(size_t)row * 64 + lane];
            ((ushort2*)rowp)[lane] = make_ushort2(f2bf(v.x), f2bf(v.y));
            float s = v.x * v.x + v.y * v.y;
#pragma unroll
            for (int o = 32; o; o >>= 1) s += __shfl_xor(s, o, 64);
            float x2w = s - w[row];
            if (lane == 0) x2wf[row] = x2w;
            if (lane < 8) ((uint*)rowp)[64 + lane] = (lane == 0) ? packx2(x2w) : 0u;
        } else {
            ((ushort2*)rowp)[lane] = make_ushort2(0, 0);      // sentinel: zero data
            if (lane < 8) ((uint*)rowp)[64 + lane] = (lane == 0) ? packx2(1e30f) : 0u;
        }
    } else {
        int qb = blockIdx.x - nblocksA;
        int row = qb * 4 + wave;
        int tid = qb * 256 + threadIdx.x;
        if (tid < m) cnt[tid] = 0;
        if (row >= m) return;
        float2 v = ((const float2*)Xt)[(size_t)row * 64 + lane];
        ((ushort2*)Xtb)[(size_t)row * 64 + lane] = make_ushort2(f2bf(v.x), f2bf(v.y));
        float s = v.x * v.x + v.y * v.y;
#pragma unroll
        for (int o = 32; o; o >>= 1) s += __shfl_xor(s, o, 64);
        if (lane == 0) q2f[row] = s;
    }
}

__device__ __forceinline__ void emit_cand(int q, int c, int* cnt, int* buf) {
    int pos = atomicAdd(&cnt[q], 1);
    if (pos < CAP) buf[q * CAP + pos] = c;
}

// ---------- main GEMM pass ----------
// 512 blocks = 128 segs x 4 query-blocks = 2 blocks/CU. Block: 4 waves x 128 queries each.
// Wave tile: 32 cands x 128 queries per k-step (4 MFMAs), B in regs.
// A staging: plain global->VGPR loads + ds_write_b128 double-buffer, ONE __syncthreads per
// tile (write bufA / barrier / load-next + compute bufA; 2-buffer rotation => the barrier
// chain already orders iter t+2's write-A after iter t's reads-A). No global_load_lds.
// acc = q.x - 0.5*x2w  =>  s = -2*acc.
template<int PASS>
__global__ __launch_bounds__(256, 2) void nd_pass(
        const ushort* __restrict__ Xbp, const ushort* __restrict__ Xtb,
        const float* __restrict__ tau, float* __restrict__ minbuf,
        int* __restrict__ cnt, int* __restrict__ buf, int m) {
    __shared__ __align__(16) ushort As[2 * BUFU];   // 2 x 9216 B

    const int t = threadIdx.x;
    const int l = t & 63, wv = t >> 6;
    const int half = l >> 5;
    const int seg = blockIdx.x;
    const int qbase = blockIdx.y * 512 + wv * 128;
    const int q0 = qbase + (l & 31);                 // query for qsub 0 (qsub s -> +32*s)
    const int tile0 = seg * NT;
    // swizzled k-unit selector for compute reads: flip half by row-bit2
    const int halfx = half ^ ((l >> 2) & 1);

    // preload B fragments: [kstep][qsub]
    short8 Bf[9][4];
#pragma unroll
    for (int s = 0; s < 8; ++s)
#pragma unroll
        for (int qs = 0; qs < 4; ++qs)
            Bf[s][qs] = *(const short8*)(Xtb + (size_t)(q0 + qs * 32) * D + s * 16 + half * 8);
    {
        short8 z = (short8)(short)0;
        if (l < 32) { z[0] = (short)0xBF00; z[1] = (short)0xBF00; }  // -0.5 at k=128,129
#pragma unroll
        for (int qs = 0; qs < 4; ++qs) Bf[8][qs] = z;
    }

    float tp[4];
    float mx[4];
#pragma unroll
    for (int qs = 0; qs < 4; ++qs) {
        tp[qs] = (PASS == 2) ? (-0.5f * tau[q0 + qs * 32]) : 0.f;
        mx[qs] = -INFINITY;
    }

    // staging mapping (loop-invariant): thread t owns global units t, 256+t, and (t<64) 512+t
    const int u0 = t, u1 = 256 + t, u2 = 512 + (t & 63);
    const int L0 = lds_unit(u0) * 8, L1 = lds_unit(u1) * 8, L2 = lds_unit(u2) * 8;
    const uint4* Xg = (const uint4*)Xbp;

    // load tile0 into regs
    uint4 r0 = Xg[(size_t)tile0 * TUNITS + u0];
    uint4 r1 = Xg[(size_t)tile0 * TUNITS + u1];
    uint4 r2 = make_uint4(0, 0, 0, 0);
    if (t < 64) r2 = Xg[(size_t)tile0 * TUNITS + u2];

    for (int t2 = 0; t2 < NT; ++t2) {
        // write current tile regs -> LDS buffer t2&1
        ushort* Lb = &As[(t2 & 1) * BUFU];
        *(uint4*)&Lb[L0] = r0;
        *(uint4*)&Lb[L1] = r1;
        if (t < 64) *(uint4*)&Lb[L2] = r2;
        __syncthreads();

        // issue loads for next tile (pad rows cover the final overrun)
        const size_t gb = (size_t)(tile0 + t2 + 1) * TUNITS;
        r0 = Xg[gb + u0];
        r1 = Xg[gb + u1];
        if (t < 64) r2 = Xg[gb + u2];

        f32x16 acc0 = (f32x16)0.f, acc1 = (f32x16)0.f, acc2 = (f32x16)0.f, acc3 = (f32x16)0.f;
#pragma unroll
        for (int ks = 0; ks < 9; ++ks) {
            const int kb = (ks < 8) ? (ks * 2 + halfx) : (16 + halfx);   // swizzled unit
            short8 a = *(const short8*)&Lb[((l & 31) * 18 + kb) * 8];
            acc0 = __builtin_amdgcn_mfma_f32_32x32x16_bf16(a, Bf[ks][0], acc0, 0, 0, 0);
            acc1 = __builtin_amdgcn_mfma_f32_32x32x16_bf16(a, Bf[ks][1], acc1, 0, 0, 0);
            acc2 = __builtin_amdgcn_mfma_f32_32x32x16_bf16(a, Bf[ks][2], acc2, 0, 0, 0);
            acc3 = __builtin_amdgcn_mfma_f32_32x32x16_bf16(a, Bf[ks][3], acc3, 0, 0, 0);
        }

        // epilogue: per-qsub max of acc (s = -2*acc, so max acc == min s)
        float h[4];
#pragma unroll
        for (int qs = 0; qs < 4; ++qs) h[qs] = -INFINITY;
#pragma unroll
        for (int r = 0; r < 16; ++r) {
            h[0] = fmaxf(h[0], acc0[r]); h[1] = fmaxf(h[1], acc1[r]);
            h[2] = fmaxf(h[2], acc2[r]); h[3] = fmaxf(h[3], acc3[r]);
        }
        if (PASS == 1) {
#pragma unroll
            for (int qs = 0; qs < 4; ++qs) mx[qs] = fmaxf(mx[qs], h[qs]);
        } else {
            const int base = (tile0 + t2) * TILE_C;
            if (__any(h[0] >= tp[0])) {
#pragma unroll
                for (int r = 0; r < 16; ++r)
                    if (acc0[r] >= tp[0]) emit_cand(q0,      base + (r & 3) + 8 * (r >> 2) + 4 * half, cnt, buf);
            }
            if (__any(h[1] >= tp[1])) {
#pragma unroll
                for (int r = 0; r < 16; ++r)
                    if (acc1[r] >= tp[1]) emit_cand(q0 + 32, base + (r & 3) + 8 * (r >> 2) + 4 * half, cnt, buf);
            }
            if (__any(h[2] >= tp[2])) {
#pragma unroll
                for (int r = 0; r < 16; ++r)
                    if (acc2[r] >= tp[2]) emit_cand(q0 + 64, base + (r & 3) + 8 * (r >> 2) + 4 * half, cnt, buf);
            }
            if (__any(h[3] >= tp[3])) {
#pragma unroll
                for (int r = 0; r < 16; ++r)
                    if (acc3[r] >= tp[3]) emit_cand(q0 + 96, base + (r & 3) + 8 * (r >> 2) + 4 * half, cnt, buf);
            }
        }
    }

    if (PASS == 1) {
        size_t rowi = (size_t)(seg * 2 + half) * m;
#pragma unroll
        for (int qs = 0; qs < 4; ++qs)
            minbuf[rowi + q0 + qs * 32] = -2.f * mx[qs];
    }
}

// ---------- tau: 10th smallest of 2*NSEG stream-mins per query, + margin ----------
// block = 256 thr = 64 queries x 4 parts; each part scans 64 stream entries (coalesced),
// partial top-10s merged via LDS, one thread per query takes 10th of 40.
__global__ void tau_kernel(const float* __restrict__ minbuf, float* __restrict__ tau, int m) {
    __shared__ float sh[64 * 40];
    const int qi = threadIdx.x & 63, part = threadIdx.x >> 6;
    const int q = blockIdx.x * 64 + qi;
    float ms[KTOP];
#pragma unroll
    for (int e = 0; e < KTOP; ++e) ms[e] = INFINITY;
#pragma unroll 4
    for (int i = 0; i < 64; ++i) {
        float v = minbuf[(size_t)(part * 64 + i) * m + q];
        if (v < ms[9]) insert10s(v, ms);
    }
#pragma unroll
    for (int e = 0; e < KTOP; ++e) sh[qi * 40 + part * 10 + e] = ms[e];
    __syncthreads();
    if (threadIdx.x < 64) {
        const int qq = blockIdx.x * 64 + threadIdx.x;
        float fs[KTOP];
#pragma unroll
        for (int e = 0; e < KTOP; ++e) fs[e] = INFINITY;
        for (int x = 0; x < 40; ++x) {
            float v = sh[threadIdx.x * 40 + x];
            if (v < fs[9]) insert10s(v, fs);
        }
        tau[qq] = fs[9] + DELTA;
    }
}

// ---------- exact fp32 rescore ----------
__global__ void rescore_kernel(const float* __restrict__ Xtf, const float* __restrict__ Xf,
                               const float* __restrict__ w, const float* __restrict__ x2wf,
                               const float* __restrict__ q2f, const int* __restrict__ cnt,
                               const int* __restrict__ buf, float* __restrict__ out, int m) {
    __shared__ float sS[CAP], sW[CAP];
    const int q = blockIdx.x, l = threadIdx.x;
    const int c = min(cnt[q], CAP);
    const bool v0 = l < c, v1 = l + 64 < c;
    const int j0 = v0 ? buf[q * CAP + l] : 0;
    const int j1 = v1 ? buf[q * CAP + l + 64] : 0;
    const float4* Q4 = (const float4*)Xtf + (size_t)q * 32;
    const float4* A4 = (const float4*)Xf + (size_t)j0 * 32;
    const float4* B4 = (const float4*)Xf + (size_t)j1 * 32;
    float acc0 = 0.f, acc1 = 0.f;
#pragma unroll 8
    for (int d = 0; d < 32; ++d) {
        float4 qv = Q4[d];
        float4 a = A4[d], b = B4[d];
        acc0 = fmaf(qv.x, a.x, fmaf(qv.y, a.y, fmaf(qv.z, a.z, fmaf(qv.w, a.w, acc0))));
        acc1 = fmaf(qv.x, b.x, fmaf(qv.y, b.y, fmaf(qv.z, b.z, fmaf(qv.w, b.w, acc1))));
    }
    sS[l]      = v0 ? (x2wf[j0] - 2.f * acc0) : INFINITY;
    sW[l]      = v0 ? w[j0] : 0.f;
    sS[l + 64] = v1 ? (x2wf[j1] - 2.f * acc1) : INFINITY;
    sW[l + 64] = v1 ? w[j1] : 0.f;
    __syncthreads();
    if (l == 0) {
        float ls[KTOP], lw[KTOP];
#pragma unroll
        for (int e = 0; e < KTOP; ++e) { ls[e] = INFINITY; lw[e] = 0.f; }
        for (int i = 0; i < c; ++i)
            if (sS[i] < ls[9]) insert10(sS[i], sW[i], ls, lw);
        float q2v = q2f[q];
        float mxv = -INFINITY;
#pragma unroll
        for (int e = 0; e < KTOP; ++e) {
            if (ls[e] < 1e30f) {
                float d2 = fmaxf(q2v + ls[e] + lw[e], 0.f);
                mxv = fmaxf(mxv, lw[e] - sqrtf(d2));
            }
        }
        out[q] = mxv;
    }
}

// ---------- launch ----------
extern "C" void kernel_launch(void* const* d_in, const int* in_sizes, int n_in,
                              void* d_out, int out_size, void* d_ws, size_t ws_size,
                              hipStream_t stream) {
    const float* Xt = (const float*)d_in[0];
    const float* X  = (const float*)d_in[1];
    const float* w  = (const float*)d_in[2];
    const int m = in_sizes[0] / D;   // 2048
    const int n = in_sizes[1] / D;   // 100000

    auto align256 = [](size_t x) { return (x + 255) & ~(size_t)255; };
    char* p = (char*)d_ws;
    ushort* Xbp  = (ushort*)p;  p += align256((size_t)NPAD * ROWU * 2);     // ~29.5 MB
    ushort* Xtb  = (ushort*)p;  p += align256((size_t)m * D * 2);
    float*  x2wf = (float*)p;   p += align256((size_t)n * 4);
    float*  q2f  = (float*)p;   p += align256((size_t)m * 4);
    float*  minb = (float*)p;   p += align256((size_t)2 * NSEG * m * 4);    // 2 MB
    float*  tau  = (float*)p;   p += align256((size_t)m * 4);
    int*    cnt  = (int*)p;     p += align256((size_t)m * 4);
    int*    buf  = (int*)p;     p += align256((size_t)m * CAP * 4);

    const int nblocksA = (NPAD + 3) / 4;
    const int nblocksB = (m + 3) / 4;
    prep_kernel<<<nblocksA + nblocksB, 256, 0, stream>>>(Xt, X, w, Xbp, Xtb, x2wf, q2f, cnt, n, m, nblocksA);

    dim3 grid(NSEG, m / 512);
    nd_pass<1><<<grid, 256, 0, stream>>>(Xbp, Xtb, tau, minb, cnt, buf, m);
    tau_kernel<<<m / 64, 256, 0, stream>>>(minb, tau, m);
    nd_pass<2><<<grid, 256, 0, stream>>>(Xbp, Xtb, tau, minb, cnt, buf, m);
    rescore_kernel<<<m, 64, 0, stream>>>(Xt, X, w, x2wf, q2f, cnt, buf, (float*)d_out, m);
}